// Round 12
// baseline (255.374 us; speedup 1.0000x reference)
//
#include <hip/hip_runtime.h>
#include <hip/hip_fp16.h>

// Cone-beam backprojection, TIGRE-style geometry.
// sinogram: [B=1, C=8, A=120, V=128, U=128] f32
// angles:   [A=120] f32
// out:      [B=1, C=8, NZ=96, NY=96, NX=96] f32
//
// v9: LDS-staged detector windows. Per (block, angle) the needed detector
// patch is a small box (iu/iv are linear-fractional in (x,y) -> extremes at
// tile corners; u-span<=30, v-span<=4 for a 16x16 (x,y) x 2 z tile). Prologue
// computes per-angle boxes; the angle loop double-buffers a 6x32-record
// (3 KB) LDS window staged with coalesced 16B loads, and the bilinear corner
// reads become ds_read_b128 from LDS (2x the L1 bandwidth, no per-gather
// line walks). Inner math identical to v8 (f16 records, clamp-126, __hfma2
// chunk accumulation, fast rcp).

#define A_N   120
#define V_N   128
#define U_N   128
#define NZv   96
#define NYv   96
#define NXv   96
#define C_N   8
#define ZPT   2                          // z per thread
#define USPAN 32                         // staged window width (records)
#define VSPAN 6                          // staged window height (rows)
#define NREC  (USPAN * VSPAN)            // 192 records = 3 KB

constexpr float DSO  = 1000.0f;
constexpr float DSD  = 1500.0f;
constexpr float DVOX = 0.8f;

#define NVOX   (NZv * NYv * NXv)        // 884736
#define SINO_N (A_N * V_N * U_N)        // 1966080 per channel
#define CHUNK  12                        // angles per f16-accum chunk

struct alignas(16) H8 { __half2 h[4]; };  // 8 channels = 16 B record

// ---------------------------------------------------------------------------
// Pre-pass: [C, A, V, U] f32 -> [A, V, U, C] f16 (one 16B record per (a,v,u))
// ---------------------------------------------------------------------------
__global__ __launch_bounds__(256) void sino_to_h(
    const float* __restrict__ in, H8* __restrict__ out) {
  int idx = blockIdx.x * 256 + threadIdx.x;   // over A*V*U, exact grid
  H8 o;
#pragma unroll
  for (int i = 0; i < 4; ++i) {
    float lo = in[(size_t)(2 * i)     * SINO_N + idx];
    float hi = in[(size_t)(2 * i + 1) * SINO_N + idx];
    o.h[i] = __floats2half2_rn(lo, hi);
  }
  out[idx] = o;
}

// ---------------------------------------------------------------------------
// Backprojection: per-angle LDS-staged detector windows, double-buffered
// ---------------------------------------------------------------------------
__global__ __launch_bounds__(256) void backproject_lds(
    const H8* __restrict__ sino,
    const float* __restrict__ angles,
    float* __restrict__ out) {
  __shared__ float s_c[A_N];
  __shared__ float s_s[A_N];
  __shared__ int2  s_box[A_N];            // (u_lo, v_lo) per angle
  __shared__ H8    s_buf[2][NREC];        // double-buffered window, 6 KB

  int tid = threadIdx.x;
  int bx0 = blockIdx.x * 16, by0 = blockIdx.y * 16;
  int z0  = blockIdx.z * ZPT;
  float zf0 = ((float)z0 - (NZv - 1) * 0.5f) * DVOX;
  float zf1 = zf0 + DVOX;

  // --- prologue: trig + per-angle bounding boxes (one angle per thread) ---
  if (tid < A_N) {
    float ang = angles[tid];
    float cs = cosf(ang), sn = sinf(ang);
    s_c[tid] = cs; s_s[tid] = sn;
    float xl = ((float)bx0        - (NXv - 1) * 0.5f) * DVOX;
    float xh = ((float)(bx0 + 15) - (NXv - 1) * 0.5f) * DVOX;
    float yl = ((float)by0        - (NYv - 1) * 0.5f) * DVOX;
    float yh = ((float)(by0 + 15) - (NYv - 1) * 0.5f) * DVOX;
    // iu and mag are linear-fractional in (x,y): extremes at the 4 corners
    float xrA = xl*cs + yl*sn, yrA = yl*cs - xl*sn;
    float xrB = xl*cs + yh*sn, yrB = yh*cs - xl*sn;
    float xrC = xh*cs + yl*sn, yrC = yl*cs - xh*sn;
    float xrD = xh*cs + yh*sn, yrD = yh*cs - xh*sn;
    float mA = DSD * __builtin_amdgcn_rcpf(DSO - xrA);
    float mB = DSD * __builtin_amdgcn_rcpf(DSO - xrB);
    float mC = DSD * __builtin_amdgcn_rcpf(DSO - xrC);
    float mD = DSD * __builtin_amdgcn_rcpf(DSO - xrD);
    float umin = fminf(fminf(yrA*mA, yrB*mB), fminf(yrC*mC, yrD*mD))
               + (U_N - 1) * 0.5f;
    float mmin = fminf(fminf(mA, mB), fminf(mC, mD));
    float mmax = fmaxf(fmaxf(mA, mB), fmaxf(mC, mD));
    float vmin = fminf(fminf(zf0*mmin, zf0*mmax), fminf(zf1*mmin, zf1*mmax))
               + (V_N - 1) * 0.5f;
    int ulo = min(max((int)floorf(umin) - 1, 0), U_N - USPAN);  // 0..96
    int vlo = min(max((int)floorf(vmin) - 1, 0), V_N - VSPAN);  // 0..122
    s_box[tid] = make_int2(ulo, vlo);
  }
  __syncthreads();

  // wave-level 8x8 (x,y) tile; block = 2x2 waves = 16x16 tile
  int lid = tid & 63, wv = tid >> 6;
  int x = bx0 + (wv & 1) * 8 + (lid & 7);
  int y = by0 + (wv >> 1) * 8 + (lid >> 3);
  float xf = ((float)x - (NXv - 1) * 0.5f) * DVOX;
  float yf = ((float)y - (NYv - 1) * 0.5f) * DVOX;
  float zf[ZPT] = { zf0, zf1 };

  int sr = tid >> 5, scol = tid & 31;     // staging (row, col) for tid<192

  // stage angle 0
  if (tid < NREC) {
    int2 b0 = s_box[0];
    s_buf[0][tid] = sino[(size_t)((b0.y + sr) * U_N) + b0.x + scol];
  }
  __syncthreads();

  float2  accf[ZPT][4];
  __half2 acch[ZPT][4];
#pragma unroll
  for (int k = 0; k < ZPT; ++k)
#pragma unroll
    for (int i = 0; i < 4; ++i) {
      accf[k][i] = make_float2(0.0f, 0.0f);
      acch[k][i] = __float2half2_rn(0.0f);
    }

  for (int chnk = 0; chnk < A_N / CHUNK; ++chnk) {
    for (int j = 0; j < CHUNK; ++j) {
      int a = chnk * CHUNK + j;
      bool more = (a + 1 < A_N);

      // issue next-angle staging load early (hides under compute)
      H8 nxt;
      if (more && tid < NREC) {
        int2 bn = s_box[a + 1];
        nxt = sino[(size_t)(((a + 1) * V_N + bn.y + sr) * U_N) + bn.x + scol];
      }

      // compute angle a from s_buf[a&1]
      int2 bc = s_box[a];
      float cs = s_c[a], sn = s_s[a];
      float xr  = xf * cs + yf * sn;
      float yr  = yf * cs - xf * sn;
      float mag = DSD * __builtin_amdgcn_rcpf(DSO - xr);
      float w   = mag * mag;
      float iu  = yr * mag + (U_N - 1) * 0.5f;
      bool uok  = (iu >= 0.0f) && (iu <= (float)(U_N - 1));
      float iuc = fminf(fmaxf(iu, 0.0f), (float)(U_N - 1));
      float u0f = fminf(floorf(iuc), (float)(U_N - 2));
      float fu  = iuc - u0f;
      float gu  = 1.0f - fu;
      int u0    = (int)u0f;
      float wu  = uok ? w : 0.0f;
      int ur    = min(max(u0 - bc.x, 0), USPAN - 2);
      const H8* bufc = s_buf[a & 1];

#pragma unroll
      for (int k = 0; k < ZPT; ++k) {
        float iv  = fmaf(zf[k], mag, (V_N - 1) * 0.5f);
        bool ok   = (iv >= 0.0f) && (iv <= (float)(V_N - 1));
        float ivc = fminf(fmaxf(iv, 0.0f), (float)(V_N - 1));
        float v0f = fminf(floorf(ivc), (float)(V_N - 2));
        float fv  = ivc - v0f;
        int v0    = (int)v0f;
        float wz  = ok ? wu : 0.0f;
        float wv0 = wz * (1.0f - fv);
        float wv1 = wz * fv;

        __half2 h00 = __float2half2_rn(wv0 * gu);
        __half2 h01 = __float2half2_rn(wv0 * fu);
        __half2 h10 = __float2half2_rn(wv1 * gu);
        __half2 h11 = __float2half2_rn(wv1 * fu);

        int vr = min(max(v0 - bc.y, 0), VSPAN - 2);
        const H8* p = bufc + vr * USPAN + ur;   // ds_read_b128 x4
        H8 c00 = p[0];
        H8 c01 = p[1];
        H8 c10 = p[USPAN];
        H8 c11 = p[USPAN + 1];

#pragma unroll
        for (int i = 0; i < 4; ++i) {
          acch[k][i] = __hfma2(c00.h[i], h00,
                       __hfma2(c01.h[i], h01,
                       __hfma2(c10.h[i], h10,
                       __hfma2(c11.h[i], h11, acch[k][i]))));
        }
      }

      // write next window into the other buffer, then sync
      if (more && tid < NREC) s_buf[(a + 1) & 1][tid] = nxt;
      __syncthreads();
    }
    // flush f16 chunk into f32 master accumulators
#pragma unroll
    for (int k = 0; k < ZPT; ++k)
#pragma unroll
      for (int i = 0; i < 4; ++i) {
        float2 sf = __half22float2(acch[k][i]);
        accf[k][i].x += sf.x;
        accf[k][i].y += sf.y;
        acch[k][i] = __float2half2_rn(0.0f);
      }
  }

#pragma unroll
  for (int k = 0; k < ZPT; ++k) {
    int vi = ((z0 + k) * NYv + y) * NXv + x;
#pragma unroll
    for (int i = 0; i < 4; ++i) {
      out[(size_t)(2 * i)     * NVOX + vi] = accf[k][i].x;
      out[(size_t)(2 * i + 1) * NVOX + vi] = accf[k][i].y;
    }
  }
}

// ---------------------------------------------------------------------------
// Fallback: direct [C][A][V][U] f32 layout (if workspace too small)
// ---------------------------------------------------------------------------
__global__ __launch_bounds__(256) void backproject_direct(
    const float* __restrict__ sino,
    const float* __restrict__ angles,
    float* __restrict__ out) {
  __shared__ float s_c[A_N];
  __shared__ float s_s[A_N];
  int tid = threadIdx.x;
  if (tid < A_N) {
    float a = angles[tid];
    s_c[tid] = cosf(a);
    s_s[tid] = sinf(a);
  }
  __syncthreads();

  int vi = blockIdx.x * 256 + tid;
  int x = vi % NXv;
  int t = vi / NXv;
  int y = t % NYv;
  int z = t / NYv;

  float xf = ((float)x - (NXv - 1) * 0.5f) * DVOX;
  float yf = ((float)y - (NYv - 1) * 0.5f) * DVOX;
  float zf = ((float)z - (NZv - 1) * 0.5f) * DVOX;

  float acc[C_N];
#pragma unroll
  for (int c = 0; c < C_N; ++c) acc[c] = 0.0f;

  for (int a = 0; a < A_N; ++a) {
    float cs = s_c[a], sn = s_s[a];
    float xr = xf * cs + yf * sn;
    float yr = yf * cs - xf * sn;
    float mag = DSD / (DSO - xr);
    float iu = yr * mag + (U_N - 1) * 0.5f;
    float iv = zf * mag + (V_N - 1) * 0.5f;
    if (iu < 0.0f || iu > (float)(U_N - 1) || iv < 0.0f || iv > (float)(V_N - 1))
      continue;
    float u0f = floorf(iu), v0f = floorf(iv);
    float fu = iu - u0f, fv = iv - v0f;
    int u0 = (int)u0f, v0 = (int)v0f;
    int u1 = min(u0 + 1, U_N - 1);
    int v1 = min(v0 + 1, V_N - 1);
    float w = mag * mag;
    float w00 = w * (1.0f - fv) * (1.0f - fu);
    float w01 = w * (1.0f - fv) * fu;
    float w10 = w * fv * (1.0f - fu);
    float w11 = w * fv * fu;

    int b00 = (a * V_N + v0) * U_N + u0;
    int b01 = (a * V_N + v0) * U_N + u1;
    int b10 = (a * V_N + v1) * U_N + u0;
    int b11 = (a * V_N + v1) * U_N + u1;
#pragma unroll
    for (int c = 0; c < C_N; ++c) {
      const float* pc = sino + (size_t)c * SINO_N;
      acc[c] += w00 * pc[b00] + w01 * pc[b01] + w10 * pc[b10] + w11 * pc[b11];
    }
  }

#pragma unroll
  for (int c = 0; c < C_N; ++c)
    out[(size_t)c * NVOX + vi] = acc[c];
}

extern "C" void kernel_launch(void* const* d_in, const int* in_sizes, int n_in,
                              void* d_out, int out_size, void* d_ws, size_t ws_size,
                              hipStream_t stream) {
  const float* sino   = (const float*)d_in[0];
  const float* angles = (const float*)d_in[1];
  float* out = (float*)d_out;

  size_t need = (size_t)SINO_N * sizeof(H8);   // 31.5 MB
  if (ws_size >= need) {
    H8* sino_h = (H8*)d_ws;
    sino_to_h<<<SINO_N / 256, 256, 0, stream>>>(sino, sino_h);
    dim3 grid(NXv / 16, NYv / 16, NZv / ZPT);   // (6, 6, 48)
    backproject_lds<<<grid, 256, 0, stream>>>(sino_h, angles, out);
  } else {
    backproject_direct<<<NVOX / 256, 256, 0, stream>>>(sino, angles, out);
  }
}

// Round 13
// 230.487 us; speedup vs baseline: 1.1080x; 1.1080x over previous
//
#include <hip/hip_runtime.h>
#include <hip/hip_fp16.h>

// Cone-beam backprojection, TIGRE-style geometry.
// sinogram: [B=1, C=8, A=120, V=128, U=128] f32
// angles:   [A=120] f32
// out:      [B=1, C=8, NZ=96, NY=96, NX=96] f32
//
// v10: v8 (best: 230us) + bijective XCD-aware block swizzle. Grid flattened
// to 1728 blocks; logical = (hw%8)*216 + hw/8 gives each XCD 216 consecutive
// logical blocks = 6 complete z-slabs whose detector footprint then stays in
// that XCD's 4MB L2 (v8 round-robined slab-mates across XCDs -> 3.2x HBM
// refetch, FETCH 102MB). Inner loop identical to v8: 8x8 (x,y) wave tiles,
// z-pair, f16 [A][V][U][C] records, clamp-126 single-base corners, __hfma2
// chunk accumulation, fast rcp.

#define A_N   120
#define V_N   128
#define U_N   128
#define NZv   96
#define NYv   96
#define NXv   96
#define C_N   8
#define ZPT   2                          // z per thread

constexpr float DSO  = 1000.0f;
constexpr float DSD  = 1500.0f;
constexpr float DVOX = 0.8f;

#define NVOX   (NZv * NYv * NXv)        // 884736
#define SINO_N (A_N * V_N * U_N)        // 1966080 per channel
#define CHUNK  12                        // angles per f16-accum chunk
#define NWG    1728                      // (96/16)*(96/16)*(96/2)
#define NXCD   8
#define CPX    (NWG / NXCD)              // 216, exact (1728 % 8 == 0)

struct alignas(16) H8 { __half2 h[4]; };  // 8 channels = 16 B record

// ---------------------------------------------------------------------------
// Pre-pass: [C, A, V, U] f32 -> [A, V, U, C] f16 (one 16B record per (a,v,u))
// ---------------------------------------------------------------------------
__global__ __launch_bounds__(256) void sino_to_h(
    const float* __restrict__ in, H8* __restrict__ out) {
  int idx = blockIdx.x * 256 + threadIdx.x;   // over A*V*U, exact grid
  H8 o;
#pragma unroll
  for (int i = 0; i < 4; ++i) {
    float lo = in[(size_t)(2 * i)     * SINO_N + idx];
    float hi = in[(size_t)(2 * i + 1) * SINO_N + idx];
    o.h[i] = __floats2half2_rn(lo, hi);
  }
  out[idx] = o;
}

// ---------------------------------------------------------------------------
// Backprojection: XCD-swizzled blocks, 8x8 (x,y) wave tiles, z-pair/thread
// ---------------------------------------------------------------------------
__global__ __launch_bounds__(256) void backproject_x(
    const H8* __restrict__ sino,
    const float* __restrict__ angles,
    float* __restrict__ out) {
  __shared__ float s_c[A_N];
  __shared__ float s_s[A_N];
  int tid = threadIdx.x;
  if (tid < A_N) {
    float a = angles[tid];
    s_c[tid] = cosf(a);
    s_s[tid] = sinf(a);
  }
  __syncthreads();

  // Bijective XCD swizzle: hw round-robins over 8 XCDs; give XCD k logical
  // blocks [k*216, (k+1)*216) = z-slabs [6k, 6k+6) -> slab footprint L2-local.
  int hw      = blockIdx.x;
  int logical = (hw & 7) * CPX + (hw >> 3);
  int slab    = logical / 36;               // 0..47  (z-pair index)
  int rem     = logical % 36;
  int bx0     = (rem % 6) * 16;
  int by0     = (rem / 6) * 16;
  int z0      = slab * ZPT;

  // wave-level 8x8 (x,y) tile; block = 2x2 waves = 16x16 tile
  int lid = tid & 63;
  int wv  = tid >> 6;                        // 0..3
  int x   = bx0 + (wv & 1) * 8 + (lid & 7);
  int y   = by0 + (wv >> 1) * 8 + (lid >> 3);

  float xf = ((float)x - (NXv - 1) * 0.5f) * DVOX;
  float yf = ((float)y - (NYv - 1) * 0.5f) * DVOX;
  float zf[ZPT];
#pragma unroll
  for (int k = 0; k < ZPT; ++k)
    zf[k] = ((float)(z0 + k) - (NZv - 1) * 0.5f) * DVOX;

  float2  accf[ZPT][4];                       // f32 master accumulators
  __half2 acch[ZPT][4];                       // f16 chunk accumulators
#pragma unroll
  for (int k = 0; k < ZPT; ++k)
#pragma unroll
    for (int i = 0; i < 4; ++i) {
      accf[k][i] = make_float2(0.0f, 0.0f);
      acch[k][i] = __float2half2_rn(0.0f);
    }

  for (int chnk = 0; chnk < A_N / CHUNK; ++chnk) {
#pragma unroll 2
    for (int j = 0; j < CHUNK; ++j) {
      int a = chnk * CHUNK + j;
      float cs = s_c[a], sn = s_s[a];
      float xr  = xf * cs + yf * sn;
      float yr  = yf * cs - xf * sn;
      float mag = DSD * __builtin_amdgcn_rcpf(DSO - xr);  // fast rcp, ~1e-6 rel
      float w   = mag * mag;

      // u-interp setup shared by both z (clamp-126: u1 = u0+1 always)
      float iu  = yr * mag + (U_N - 1) * 0.5f;
      bool uok  = (iu >= 0.0f) && (iu <= (float)(U_N - 1));
      float iuc = fminf(fmaxf(iu, 0.0f), (float)(U_N - 1));
      float u0f = fminf(floorf(iuc), (float)(U_N - 2));
      float fu  = iuc - u0f;                  // in [0,1]
      float gu  = 1.0f - fu;
      int u0    = (int)u0f;
      float wu  = uok ? w : 0.0f;
      const H8* arow = sino + (size_t)(a * (V_N * U_N) + u0);

#pragma unroll
      for (int k = 0; k < ZPT; ++k) {
        float iv  = fmaf(zf[k], mag, (V_N - 1) * 0.5f);
        bool ok   = (iv >= 0.0f) && (iv <= (float)(V_N - 1));
        float ivc = fminf(fmaxf(iv, 0.0f), (float)(V_N - 1));
        float v0f = fminf(floorf(ivc), (float)(V_N - 2));
        float fv  = ivc - v0f;
        int v0    = (int)v0f;
        float wz  = ok ? wu : 0.0f;
        float wv0 = wz * (1.0f - fv);
        float wv1 = wz * fv;

        __half2 h00 = __float2half2_rn(wv0 * gu);
        __half2 h01 = __float2half2_rn(wv0 * fu);
        __half2 h10 = __float2half2_rn(wv1 * gu);
        __half2 h11 = __float2half2_rn(wv1 * fu);

        const H8* p = arow + v0 * U_N;        // imm offsets 0,16,2048,2064
        H8 c00 = p[0];
        H8 c01 = p[1];
        H8 c10 = p[U_N];
        H8 c11 = p[U_N + 1];

#pragma unroll
        for (int i = 0; i < 4; ++i) {
          acch[k][i] = __hfma2(c00.h[i], h00,
                       __hfma2(c01.h[i], h01,
                       __hfma2(c10.h[i], h10,
                       __hfma2(c11.h[i], h11, acch[k][i]))));
        }
      }
    }
    // flush f16 chunk into f32 master accumulators
#pragma unroll
    for (int k = 0; k < ZPT; ++k)
#pragma unroll
      for (int i = 0; i < 4; ++i) {
        float2 sf = __half22float2(acch[k][i]);
        accf[k][i].x += sf.x;
        accf[k][i].y += sf.y;
        acch[k][i] = __float2half2_rn(0.0f);
      }
  }

#pragma unroll
  for (int k = 0; k < ZPT; ++k) {
    int vi = ((z0 + k) * NYv + y) * NXv + x;
#pragma unroll
    for (int i = 0; i < 4; ++i) {
      out[(size_t)(2 * i)     * NVOX + vi] = accf[k][i].x;
      out[(size_t)(2 * i + 1) * NVOX + vi] = accf[k][i].y;
    }
  }
}

// ---------------------------------------------------------------------------
// Fallback: direct [C][A][V][U] f32 layout (if workspace too small)
// ---------------------------------------------------------------------------
__global__ __launch_bounds__(256) void backproject_direct(
    const float* __restrict__ sino,
    const float* __restrict__ angles,
    float* __restrict__ out) {
  __shared__ float s_c[A_N];
  __shared__ float s_s[A_N];
  int tid = threadIdx.x;
  if (tid < A_N) {
    float a = angles[tid];
    s_c[tid] = cosf(a);
    s_s[tid] = sinf(a);
  }
  __syncthreads();

  int vi = blockIdx.x * 256 + tid;
  int x = vi % NXv;
  int t = vi / NXv;
  int y = t % NYv;
  int z = t / NYv;

  float xf = ((float)x - (NXv - 1) * 0.5f) * DVOX;
  float yf = ((float)y - (NYv - 1) * 0.5f) * DVOX;
  float zf = ((float)z - (NZv - 1) * 0.5f) * DVOX;

  float acc[C_N];
#pragma unroll
  for (int c = 0; c < C_N; ++c) acc[c] = 0.0f;

  for (int a = 0; a < A_N; ++a) {
    float cs = s_c[a], sn = s_s[a];
    float xr = xf * cs + yf * sn;
    float yr = yf * cs - xf * sn;
    float mag = DSD / (DSO - xr);
    float iu = yr * mag + (U_N - 1) * 0.5f;
    float iv = zf * mag + (V_N - 1) * 0.5f;
    if (iu < 0.0f || iu > (float)(U_N - 1) || iv < 0.0f || iv > (float)(V_N - 1))
      continue;
    float u0f = floorf(iu), v0f = floorf(iv);
    float fu = iu - u0f, fv = iv - v0f;
    int u0 = (int)u0f, v0 = (int)v0f;
    int u1 = min(u0 + 1, U_N - 1);
    int v1 = min(v0 + 1, V_N - 1);
    float w = mag * mag;
    float w00 = w * (1.0f - fv) * (1.0f - fu);
    float w01 = w * (1.0f - fv) * fu;
    float w10 = w * fv * (1.0f - fu);
    float w11 = w * fv * fu;

    int b00 = (a * V_N + v0) * U_N + u0;
    int b01 = (a * V_N + v0) * U_N + u1;
    int b10 = (a * V_N + v1) * U_N + u0;
    int b11 = (a * V_N + v1) * U_N + u1;
#pragma unroll
    for (int c = 0; c < C_N; ++c) {
      const float* pc = sino + (size_t)c * SINO_N;
      acc[c] += w00 * pc[b00] + w01 * pc[b01] + w10 * pc[b10] + w11 * pc[b11];
    }
  }

#pragma unroll
  for (int c = 0; c < C_N; ++c)
    out[(size_t)c * NVOX + vi] = acc[c];
}

extern "C" void kernel_launch(void* const* d_in, const int* in_sizes, int n_in,
                              void* d_out, int out_size, void* d_ws, size_t ws_size,
                              hipStream_t stream) {
  const float* sino   = (const float*)d_in[0];
  const float* angles = (const float*)d_in[1];
  float* out = (float*)d_out;

  size_t need = (size_t)SINO_N * sizeof(H8);   // 31.5 MB
  if (ws_size >= need) {
    H8* sino_h = (H8*)d_ws;
    sino_to_h<<<SINO_N / 256, 256, 0, stream>>>(sino, sino_h);
    backproject_x<<<NWG, 256, 0, stream>>>(sino_h, angles, out);
  } else {
    backproject_direct<<<NVOX / 256, 256, 0, stream>>>(sino, angles, out);
  }
}

// Round 14
// 230.238 us; speedup vs baseline: 1.1092x; 1.0011x over previous
//
#include <hip/hip_runtime.h>
#include <hip/hip_fp16.h>

// Cone-beam backprojection, TIGRE-style geometry.
// sinogram: [B=1, C=8, A=120, V=128, U=128] f32
// angles:   [A=120] f32
// out:      [B=1, C=8, NZ=96, NY=96, NX=96] f32
//
// v11: v10 (230us; XCD-swizzled, FETCH 17MB, TA-pipe-bound at ~21cyc/gather)
// + quad-compact lane remap: TA coalescing is per-16-lane quad; the old
// lid->(lid&7, lid>>3) map made each quad an 8x2 sliver (u-span ~12 records).
// New map makes each quad a 4x4 tile (u-span ~9.6, fewer v-rows) -> ~20%
// fewer 64B line-walks per gather. Wave still covers the same 8x8 tile;
// all other math byte-identical to v10.

#define A_N   120
#define V_N   128
#define U_N   128
#define NZv   96
#define NYv   96
#define NXv   96
#define C_N   8
#define ZPT   2                          // z per thread

constexpr float DSO  = 1000.0f;
constexpr float DSD  = 1500.0f;
constexpr float DVOX = 0.8f;

#define NVOX   (NZv * NYv * NXv)        // 884736
#define SINO_N (A_N * V_N * U_N)        // 1966080 per channel
#define CHUNK  12                        // angles per f16-accum chunk
#define NWG    1728                      // (96/16)*(96/16)*(96/2)
#define NXCD   8
#define CPX    (NWG / NXCD)              // 216, exact (1728 % 8 == 0)

struct alignas(16) H8 { __half2 h[4]; };  // 8 channels = 16 B record

// ---------------------------------------------------------------------------
// Pre-pass: [C, A, V, U] f32 -> [A, V, U, C] f16 (one 16B record per (a,v,u))
// ---------------------------------------------------------------------------
__global__ __launch_bounds__(256) void sino_to_h(
    const float* __restrict__ in, H8* __restrict__ out) {
  int idx = blockIdx.x * 256 + threadIdx.x;   // over A*V*U, exact grid
  H8 o;
#pragma unroll
  for (int i = 0; i < 4; ++i) {
    float lo = in[(size_t)(2 * i)     * SINO_N + idx];
    float hi = in[(size_t)(2 * i + 1) * SINO_N + idx];
    o.h[i] = __floats2half2_rn(lo, hi);
  }
  out[idx] = o;
}

// ---------------------------------------------------------------------------
// Backprojection: XCD-swizzled blocks, quad-compact 8x8 wave tiles, z-pair
// ---------------------------------------------------------------------------
__global__ __launch_bounds__(256) void backproject_q(
    const H8* __restrict__ sino,
    const float* __restrict__ angles,
    float* __restrict__ out) {
  __shared__ float s_c[A_N];
  __shared__ float s_s[A_N];
  int tid = threadIdx.x;
  if (tid < A_N) {
    float a = angles[tid];
    s_c[tid] = cosf(a);
    s_s[tid] = sinf(a);
  }
  __syncthreads();

  // Bijective XCD swizzle: XCD k gets logical blocks [k*216,(k+1)*216) =
  // z-slabs [6k, 6k+6) -> slab detector footprint stays in its own L2.
  int hw      = blockIdx.x;
  int logical = (hw & 7) * CPX + (hw >> 3);
  int slab    = logical / 36;               // 0..47  (z-pair index)
  int rem     = logical % 36;
  int bx0     = (rem % 6) * 16;
  int by0     = (rem / 6) * 16;
  int z0      = slab * ZPT;

  // quad-compact lane map: each 16-lane quad is a 4x4 (x,y) tile;
  // quads tile the wave's 8x8 region (2x2 quads); block = 2x2 waves = 16x16.
  int lid = tid & 63;
  int wv  = tid >> 6;                        // 0..3
  int lx  = (lid & 3)        + ((lid >> 4) & 1) * 4;
  int ly  = ((lid >> 2) & 3) + ((lid >> 5) & 1) * 4;
  int x   = bx0 + (wv & 1) * 8 + lx;
  int y   = by0 + (wv >> 1) * 8 + ly;

  float xf = ((float)x - (NXv - 1) * 0.5f) * DVOX;
  float yf = ((float)y - (NYv - 1) * 0.5f) * DVOX;
  float zf[ZPT];
#pragma unroll
  for (int k = 0; k < ZPT; ++k)
    zf[k] = ((float)(z0 + k) - (NZv - 1) * 0.5f) * DVOX;

  float2  accf[ZPT][4];                       // f32 master accumulators
  __half2 acch[ZPT][4];                       // f16 chunk accumulators
#pragma unroll
  for (int k = 0; k < ZPT; ++k)
#pragma unroll
    for (int i = 0; i < 4; ++i) {
      accf[k][i] = make_float2(0.0f, 0.0f);
      acch[k][i] = __float2half2_rn(0.0f);
    }

  for (int chnk = 0; chnk < A_N / CHUNK; ++chnk) {
#pragma unroll 2
    for (int j = 0; j < CHUNK; ++j) {
      int a = chnk * CHUNK + j;
      float cs = s_c[a], sn = s_s[a];
      float xr  = xf * cs + yf * sn;
      float yr  = yf * cs - xf * sn;
      float mag = DSD * __builtin_amdgcn_rcpf(DSO - xr);  // fast rcp, ~1e-6 rel
      float w   = mag * mag;

      // u-interp setup shared by both z (clamp-126: u1 = u0+1 always)
      float iu  = yr * mag + (U_N - 1) * 0.5f;
      bool uok  = (iu >= 0.0f) && (iu <= (float)(U_N - 1));
      float iuc = fminf(fmaxf(iu, 0.0f), (float)(U_N - 1));
      float u0f = fminf(floorf(iuc), (float)(U_N - 2));
      float fu  = iuc - u0f;                  // in [0,1]
      float gu  = 1.0f - fu;
      int u0    = (int)u0f;
      float wu  = uok ? w : 0.0f;
      const H8* arow = sino + (size_t)(a * (V_N * U_N) + u0);

#pragma unroll
      for (int k = 0; k < ZPT; ++k) {
        float iv  = fmaf(zf[k], mag, (V_N - 1) * 0.5f);
        bool ok   = (iv >= 0.0f) && (iv <= (float)(V_N - 1));
        float ivc = fminf(fmaxf(iv, 0.0f), (float)(V_N - 1));
        float v0f = fminf(floorf(ivc), (float)(V_N - 2));
        float fv  = ivc - v0f;
        int v0    = (int)v0f;
        float wz  = ok ? wu : 0.0f;
        float wv0 = wz * (1.0f - fv);
        float wv1 = wz * fv;

        __half2 h00 = __float2half2_rn(wv0 * gu);
        __half2 h01 = __float2half2_rn(wv0 * fu);
        __half2 h10 = __float2half2_rn(wv1 * gu);
        __half2 h11 = __float2half2_rn(wv1 * fu);

        const H8* p = arow + v0 * U_N;        // imm offsets 0,16,2048,2064
        H8 c00 = p[0];
        H8 c01 = p[1];
        H8 c10 = p[U_N];
        H8 c11 = p[U_N + 1];

#pragma unroll
        for (int i = 0; i < 4; ++i) {
          acch[k][i] = __hfma2(c00.h[i], h00,
                       __hfma2(c01.h[i], h01,
                       __hfma2(c10.h[i], h10,
                       __hfma2(c11.h[i], h11, acch[k][i]))));
        }
      }
    }
    // flush f16 chunk into f32 master accumulators
#pragma unroll
    for (int k = 0; k < ZPT; ++k)
#pragma unroll
      for (int i = 0; i < 4; ++i) {
        float2 sf = __half22float2(acch[k][i]);
        accf[k][i].x += sf.x;
        accf[k][i].y += sf.y;
        acch[k][i] = __float2half2_rn(0.0f);
      }
  }

#pragma unroll
  for (int k = 0; k < ZPT; ++k) {
    int vi = ((z0 + k) * NYv + y) * NXv + x;
#pragma unroll
    for (int i = 0; i < 4; ++i) {
      out[(size_t)(2 * i)     * NVOX + vi] = accf[k][i].x;
      out[(size_t)(2 * i + 1) * NVOX + vi] = accf[k][i].y;
    }
  }
}

// ---------------------------------------------------------------------------
// Fallback: direct [C][A][V][U] f32 layout (if workspace too small)
// ---------------------------------------------------------------------------
__global__ __launch_bounds__(256) void backproject_direct(
    const float* __restrict__ sino,
    const float* __restrict__ angles,
    float* __restrict__ out) {
  __shared__ float s_c[A_N];
  __shared__ float s_s[A_N];
  int tid = threadIdx.x;
  if (tid < A_N) {
    float a = angles[tid];
    s_c[tid] = cosf(a);
    s_s[tid] = sinf(a);
  }
  __syncthreads();

  int vi = blockIdx.x * 256 + tid;
  int x = vi % NXv;
  int t = vi / NXv;
  int y = t % NYv;
  int z = t / NYv;

  float xf = ((float)x - (NXv - 1) * 0.5f) * DVOX;
  float yf = ((float)y - (NYv - 1) * 0.5f) * DVOX;
  float zf = ((float)z - (NZv - 1) * 0.5f) * DVOX;

  float acc[C_N];
#pragma unroll
  for (int c = 0; c < C_N; ++c) acc[c] = 0.0f;

  for (int a = 0; a < A_N; ++a) {
    float cs = s_c[a], sn = s_s[a];
    float xr = xf * cs + yf * sn;
    float yr = yf * cs - xf * sn;
    float mag = DSD / (DSO - xr);
    float iu = yr * mag + (U_N - 1) * 0.5f;
    float iv = zf * mag + (V_N - 1) * 0.5f;
    if (iu < 0.0f || iu > (float)(U_N - 1) || iv < 0.0f || iv > (float)(V_N - 1))
      continue;
    float u0f = floorf(iu), v0f = floorf(iv);
    float fu = iu - u0f, fv = iv - v0f;
    int u0 = (int)u0f, v0 = (int)v0f;
    int u1 = min(u0 + 1, U_N - 1);
    int v1 = min(v0 + 1, V_N - 1);
    float w = mag * mag;
    float w00 = w * (1.0f - fv) * (1.0f - fu);
    float w01 = w * (1.0f - fv) * fu;
    float w10 = w * fv * (1.0f - fu);
    float w11 = w * fv * fu;

    int b00 = (a * V_N + v0) * U_N + u0;
    int b01 = (a * V_N + v0) * U_N + u1;
    int b10 = (a * V_N + v1) * U_N + u0;
    int b11 = (a * V_N + v1) * U_N + u1;
#pragma unroll
    for (int c = 0; c < C_N; ++c) {
      const float* pc = sino + (size_t)c * SINO_N;
      acc[c] += w00 * pc[b00] + w01 * pc[b01] + w10 * pc[b10] + w11 * pc[b11];
    }
  }

#pragma unroll
  for (int c = 0; c < C_N; ++c)
    out[(size_t)c * NVOX + vi] = acc[c];
}

extern "C" void kernel_launch(void* const* d_in, const int* in_sizes, int n_in,
                              void* d_out, int out_size, void* d_ws, size_t ws_size,
                              hipStream_t stream) {
  const float* sino   = (const float*)d_in[0];
  const float* angles = (const float*)d_in[1];
  float* out = (float*)d_out;

  size_t need = (size_t)SINO_N * sizeof(H8);   // 31.5 MB
  if (ws_size >= need) {
    H8* sino_h = (H8*)d_ws;
    sino_to_h<<<SINO_N / 256, 256, 0, stream>>>(sino, sino_h);
    backproject_q<<<NWG, 256, 0, stream>>>(sino_h, angles, out);
  } else {
    backproject_direct<<<NVOX / 256, 256, 0, stream>>>(sino, angles, out);
  }
}